// Round 2
// baseline (1918.980 us; speedup 1.0000x reference)
//
#include <hip/hip_runtime.h>

typedef __attribute__((ext_vector_type(8))) __bf16 bf16x8;
typedef __attribute__((ext_vector_type(4))) float  f32x4;

#define DEVFN __device__ __forceinline__

constexpr int B = 256, I = 256, H = 512, S = 64;
constexpr int G4H = 4 * H;   // 2048 encoder gate cols
constexpr int G4I = 4 * I;   // 1024 decoder gate cols
constexpr int G3I = 3 * I;   // 768 packed decoder gate cols (i,g,o)

// ---- k_enc dynamic-LDS map (bytes) ----
constexpr int STASH_OFF = 131072;  // Whh slice: 128 cols x 1024 B, then 16 KB gate stash
constexpr int LDS_ENC   = 147456;  // 144 KB <= 160 KB -> 1 block/CU

struct Params {
  const float* x;        // [B][I][S]      fp32
  const float* Wih_enc;  // [S][4H][I]     fp32
  const float* Whh_enc;  // [S][4H][H]     fp32
  const float* bih_enc;  // [S][4H]
  const float* bhh_enc;  // [S][4H]
  const float* Wih_dec;  // [S][4I][H]     fp32
  const float* bih_dec;  // [S][4I]
  const float* bhh_dec;  // [S][4I]
  __bf16* xT;             // [S][B][I]  bf16
  float*  h32a; float*  h32b;   // [B][H] ping-pong (fp32 h for cell update)
  __bf16* h16a; __bf16* h16b;   // [B][H] ping-pong (bf16 h for MFMA)
  __bf16* enc;            // [S][B][H]  bf16: elu(h_t), then AR-filtered in place
  float*  hd;             // [S][B][I]  fp32
  __bf16* Whh16;          // [S][4H][H] bf16 (preconverted)
  __bf16* Wdec16;         // [S][3I][H] bf16 (preconverted, gates i,g,o packed)
  float*  xg;             // [S][B][4H] fp32: bias + x_t@Wih^T (precomputed)
  unsigned* sync;         // [8] per-bh arrival counters (monotone)
  float*  out;            // [B][I][S]  fp32
};

DEVFN float sigmoidf_(float x) { return 1.0f / (1.0f + __expf(-x)); }
DEVFN float tanhf_(float x) { float e = __expf(2.0f * x); return 1.0f - 2.0f / (e + 1.0f); }

// load 8 fp32, convert to bf16x8 (RNE via (__bf16) cast)
DEVFN bf16x8 loadw8(const float* p) {
  float4 a = *(const float4*)p;
  float4 b = *(const float4*)(p + 4);
  bf16x8 r;
  r[0] = (__bf16)a.x; r[1] = (__bf16)a.y; r[2] = (__bf16)a.z; r[3] = (__bf16)a.w;
  r[4] = (__bf16)b.x; r[5] = (__bf16)b.y; r[6] = (__bf16)b.z; r[7] = (__bf16)b.w;
  return r;
}

// async global->LDS, 16B per lane. LDS dest must be linear in lane order.
DEVFN void dma16(const void* g, void* l) {
  __builtin_amdgcn_global_load_lds((const __attribute__((address_space(1))) unsigned int*)g,
                                   (__attribute__((address_space(3))) unsigned int*)l, 16, 0, 0);
}

// ---------------- weight preconversion kernels ----------------
__global__ __launch_bounds__(512) void k_cvt(const float* __restrict__ src,
                                             __bf16* __restrict__ dst) {
  size_t i = ((size_t)blockIdx.x * 512 + threadIdx.x) * 8;
  *(bf16x8*)(dst + i) = loadw8(src + i);
}

// Wih_dec [S][4I][H] fp32 -> packed [S][3I][H] bf16, gates {i,g,o}
__global__ __launch_bounds__(512) void k_cvt_dec(const float* __restrict__ src,
                                                 __bf16* __restrict__ dst) {
  size_t idx = (size_t)blockIdx.x * 512 + threadIdx.x;   // [0, 3145728)
  int k8  = (int)(idx & 63) * 8;
  int row = (int)(idx >> 6);                             // s*768 + g3*256 + j
  int s = row / 768; int rr = row - s * 768;
  int g3 = rr >> 8; int j = rr & 255;
  int gate = (g3 == 0) ? 0 : (g3 + 1);                   // {0,2,3} in 4I layout
  const float* sp = src + (((size_t)s * G4I) + (size_t)gate * I + j) * H + k8;
  *(bf16x8*)(dst + (size_t)row * H + k8) = loadw8(sp);
}

// ---------------- phase: transpose x[B][I][S] (fp32) -> xT[S][B][I] (bf16) ----
DEVFN void phase_transpose(const Params& P, int job, float* smemf) {
  __bf16* tile = (__bf16*)smemf;            // [64][66] bf16
  const int tid = threadIdx.x;
  const int b = job >> 2, i0 = (job & 3) * 64;
#pragma unroll
  for (int rep = 0; rep < 8; ++rep) {
    int idx = tid + rep * 512;
    int ii = idx >> 6, tt = idx & 63;
    tile[ii * 66 + tt] = (__bf16)P.x[((size_t)(b * I + i0 + ii)) * S + tt];
  }
  __syncthreads();
#pragma unroll
  for (int rep = 0; rep < 8; ++rep) {
    int idx = tid + rep * 512;
    int tt = idx >> 6, ii = idx & 63;
    P.xT[((size_t)tt * B + b) * I + i0 + ii] = tile[ii * 66 + tt];
  }
}

// ---------------- x-part gates GEMM: xg[t][b][gc] = bias + x_t @ Wih[t]^T ------
// job = g*32 + bt*8 + r; (t,jt) = g*8+r (4 bt sharing a weight slice land on
// one XCD). Block: 64 b-rows x (4 gates x 32 j) = 64 x 128, K=256.
__global__ __launch_bounds__(512) void k_xg(Params P) {
  const int tid = threadIdx.x;
  const int job = blockIdx.x;
  const int g = job >> 5, bt = (job >> 3) & 3, r = job & 7;
  const int tj = g * 8 + r;                 // [0,1024) = t*16 + jt
  const int t = tj >> 4, jtl = tj & 15;
  const int b0 = bt * 64, j0 = jtl * 32;
  const int wave = tid >> 6, lane = tid & 63;
  const int rt = wave >> 1, chalf = wave & 1;
  const int ncol = lane & 15, quad = lane >> 4;
  const int arow = b0 + rt * 16 + ncol;
  const __bf16* aRow = P.xT + ((size_t)t * B + arow) * I + quad * 8;

  f32x4 acc[4];
  int gcols[4];
#pragma unroll
  for (int cc = 0; cc < 4; ++cc) {
    const int c = chalf * 4 + cc;           // col-tile in [0,8)
    const int e = c >> 1;                   // gate
    const int gcol = e * H + j0 + (c & 1) * 16 + ncol;
    gcols[cc] = gcol;
    float bias = P.bih_enc[t * G4H + gcol] + P.bhh_enc[t * G4H + gcol];
    acc[cc] = {bias, bias, bias, bias};
  }
  const float* bBase = P.Wih_enc + ((size_t)t * G4H) * I + quad * 8;
#pragma unroll
  for (int kk = 0; kk < I; kk += 32) {
    bf16x8 af = *(const bf16x8*)(aRow + kk);
#pragma unroll
    for (int cc = 0; cc < 4; ++cc) {
      bf16x8 bf = loadw8(bBase + (size_t)gcols[cc] * I + kk);
      acc[cc] = __builtin_amdgcn_mfma_f32_16x16x32_bf16(af, bf, acc[cc], 0, 0, 0);
    }
  }
  // store raw gates fp32 (C layout: row = quad*4+rr, col = ncol)
#pragma unroll
  for (int cc = 0; cc < 4; ++cc) {
#pragma unroll
    for (int rr = 0; rr < 4; ++rr) {
      const int row = b0 + rt * 16 + quad * 4 + rr;
      P.xg[((size_t)t * B + row) * G4H + gcols[cc]] = acc[cc][rr];
    }
  }
}

// ---------------- legacy encoder step (fallback path) ----------------
DEVFN void phase_step(const Params& P, int t, int job, float* smem) {
  const int tid = threadIdx.x;
  const int g = job >> 7, r = job & 7, bt = (job >> 3) & 15;
  const int jt = g * 8 + r;
  const int b0 = bt * 16, j0 = jt * 32;
  const int wave = tid >> 6, lane = tid & 63;
  const int e = wave >> 1, ct = wave & 1;
  const int ncol = lane & 15, quad = lane >> 4;
  const int gcol = e * H + j0 + ct * 16 + ncol;
  const float*  h32r = (t & 1) ? P.h32b : P.h32a;
  float*        h32w = (t & 1) ? P.h32a : P.h32b;
  const __bf16* h16r = (t & 1) ? P.h16b : P.h16a;
  __bf16*       h16w = (t & 1) ? P.h16a : P.h16b;

  float bias = P.bih_enc[t * G4H + gcol] + P.bhh_enc[t * G4H + gcol];
  f32x4 acc = {bias, bias, bias, bias};
  const int m = ncol;
  const __bf16* aRow1 = P.xT + ((size_t)t * B + b0 + m) * I + quad * 8;
  const float*  bRow1 = P.Wih_enc + ((size_t)t * G4H + gcol) * I + quad * 8;
#pragma unroll
  for (int kk = 0; kk < I; kk += 32) {
    bf16x8 af = *(const bf16x8*)(aRow1 + kk);
    bf16x8 bf = loadw8(bRow1 + kk);
    acc = __builtin_amdgcn_mfma_f32_16x16x32_bf16(af, bf, acc, 0, 0, 0);
  }
  const __bf16* aRow2 = h16r + (size_t)(b0 + m) * H + quad * 8;
  const float*  bRow2 = P.Whh_enc + ((size_t)t * G4H + gcol) * H + quad * 8;
#pragma unroll
  for (int kk = 0; kk < H; kk += 32) {
    bf16x8 af = *(const bf16x8*)(aRow2 + kk);
    bf16x8 bf = loadw8(bRow2 + kk);
    acc = __builtin_amdgcn_mfma_f32_16x16x32_bf16(af, bf, acc, 0, 0, 0);
  }
  float* sm = smem + (e * 2 + ct) * 256;
#pragma unroll
  for (int rr = 0; rr < 4; ++rr) sm[(quad * 4 + rr) * 16 + ncol] = acc[rr];
  __syncthreads();
  {
    const int row = tid >> 5, j = tid & 31;
    const int o = (j >> 4) * 256 + row * 16 + (j & 15);
    float gi = smem[o], gf = smem[512 + o], gg = smem[1024 + o], go = smem[1536 + o];
    size_t hidx = (size_t)(b0 + row) * H + j0 + j;
    float hp = h32r[hidx];
    float c  = sigmoidf_(gf) * hp + sigmoidf_(gi) * tanhf_(gg);
    float hn = sigmoidf_(go) * tanhf_(c);
    h32w[hidx] = hn;
    h16w[hidx] = (__bf16)hn;
    float el = hn > 0.0f ? hn : (__expf(hn) - 1.0f);
    P.enc[((size_t)t * B + b0 + row) * H + j0 + j] = (__bf16)el;
  }
}

// ---------------- persistent encoder: all 64 steps in one kernel ----------------
// grid 128 (<= 256 CUs at 1 block/CU -> co-residency GUARANTEED), 512 thr,
// 144 KB dynamic LDS. Block (jt,bh): 32 b-rows x 128 gate cols.
// Per step: issue Whh DMA (h-independent) -> spin on per-bh 16-block counter
// (agent-scope; __threadfence release/acquire handles cross-XCD L2 coherence)
// -> h frags from global -> 32 MFMA/wave -> epilogue -> release.
__global__ __launch_bounds__(512, 2) void k_enc(Params P) {
  extern __shared__ char sm[];
  const int tid = threadIdx.x;
  const int bx = blockIdx.x;
  const int jt = bx & 15, bh = bx >> 4;       // jt: gate-col slice; bh: b-row group
  const int b0 = bh * 32, j0 = jt * 32;
  const int wave = tid >> 6, lane = tid & 63;
  const int mt = wave >> 2, nq = wave & 3;    // mt: M-tile {0,1}; nq: gate {i,f,g,o}
  const int ncol = lane & 15, quad = lane >> 4;
  const int arow = b0 + mt * 16 + ncol;       // A row (global b)
  const int ci0 = nq * 32 + ncol, ci1 = ci0 + 16;          // LDS Whh cols
  const int swb0 = (ci0 & 7) << 4, swb1 = (ci1 & 7) << 4;  // read swizzle
  const int gc0 = nq * H + j0 + ncol, gc1 = gc0 + 16;      // gate cols
  unsigned* cnt = P.sync + bh;
  // epilogue coords: 2 consecutive j per thread
  const int erow = tid >> 4;                  // [0,32)
  const int ej = (tid & 15) * 2;

  for (int t = 0; t < S; ++t) {
    const float*  h32r = (t & 1) ? P.h32b : P.h32a;
    float*        h32w = (t & 1) ? P.h32a : P.h32b;
    const __bf16* h16r = (t & 1) ? P.h16b : P.h16a;
    __bf16*       h16w = (t & 1) ? P.h16a : P.h16b;

    // ---- issue Whh[t] slice DMA: 128 cols x 1024 B, source-swizzled
#pragma unroll
    for (int i = 0; i < 16; ++i) {
      const int d = (i * 512 + tid) * 16;
      const int ci = d >> 10, c = (d & 1023) ^ ((ci & 7) << 4);
      const int gc = (ci >> 5) * H + j0 + (ci & 31);
      dma16((const char*)(P.Whh16 + ((size_t)t * G4H + gc) * H) + c, sm + d);
    }
    // ---- xg preload (h-independent; completes during the spin)
    f32x4 acc0, acc1;
    {
      const float* xb = P.xg + ((size_t)t * B + b0 + mt * 16 + quad * 4) * G4H;
#pragma unroll
      for (int rr = 0; rr < 4; ++rr) {
        acc0[rr] = xb[(size_t)rr * G4H + gc0];
        acc1[rr] = xb[(size_t)rr * G4H + gc1];
      }
    }
    // ---- wait for h[t-1] from the 16 blocks of this bh group
    if (t > 0) {
      if (tid == 0) {
        while (__hip_atomic_load(cnt, __ATOMIC_RELAXED, __HIP_MEMORY_SCOPE_AGENT)
               < (unsigned)(16 * t))
          __builtin_amdgcn_s_sleep(2);
        __threadfence();                      // acquire: invalidate L1/L2
      }
    }
    __syncthreads();                          // broadcast + drains vmcnt(0): Whh resident
    // ---- A fragments: h[t-1] rows from global (fresh past the fence)
    bf16x8 a[16];
    {
      const __bf16* ap = h16r + (size_t)arow * H + quad * 8;
#pragma unroll
      for (int kk = 0; kk < 16; ++kk) a[kk] = *(const bf16x8*)(ap + kk * 32);
    }
    // ---- h-part MFMAs (B from LDS, swizzle-matched)
#pragma unroll
    for (int kk = 0; kk < 16; ++kk) {
      const int wo = kk * 64 + quad * 16;
      bf16x8 bq0 = *(const bf16x8*)(sm + ci0 * 1024 + (wo ^ swb0));
      bf16x8 bq1 = *(const bf16x8*)(sm + ci1 * 1024 + (wo ^ swb1));
      acc0 = __builtin_amdgcn_mfma_f32_16x16x32_bf16(a[kk], bq0, acc0, 0, 0, 0);
      acc1 = __builtin_amdgcn_mfma_f32_16x16x32_bf16(a[kk], bq1, acc1, 0, 0, 0);
    }
    // ---- stash gate tiles: [mt*8 + nq*2 + half][256]
    float* st = (float*)(sm + STASH_OFF);
#pragma unroll
    for (int rr = 0; rr < 4; ++rr) {
      st[(mt * 8 + nq * 2 + 0) * 256 + (quad * 4 + rr) * 16 + ncol] = acc0[rr];
      st[(mt * 8 + nq * 2 + 1) * 256 + (quad * 4 + rr) * 16 + ncol] = acc1[rr];
    }
    __syncthreads();
    // ---- epilogue: 32 rows x 32 j, 2 per thread
    {
      const int mt2 = erow >> 4, r15 = erow & 15;
      const size_t hbase = (size_t)(b0 + erow) * H + j0 + ej;
      float2 hp = *(const float2*)(h32r + hbase);
      float hn2[2];
#pragma unroll
      for (int u = 0; u < 2; ++u) {
        const int j = ej + u;
        const int half = j >> 4, jc = j & 15;
        const int o = r15 * 16 + jc;
        float gi = st[(mt2 * 8 + 0 + half) * 256 + o];
        float gf = st[(mt2 * 8 + 2 + half) * 256 + o];
        float gg = st[(mt2 * 8 + 4 + half) * 256 + o];
        float go = st[(mt2 * 8 + 6 + half) * 256 + o];
        float hpv = (u == 0) ? hp.x : hp.y;
        float c  = sigmoidf_(gf) * hpv + sigmoidf_(gi) * tanhf_(gg);
        float hn = sigmoidf_(go) * tanhf_(c);
        hn2[u] = hn;
        float el = hn > 0.0f ? hn : (__expf(hn) - 1.0f);
        P.enc[((size_t)t * B + b0 + erow) * H + j0 + j] = (__bf16)el;
      }
      *(float2*)(h32w + hbase) = make_float2(hn2[0], hn2[1]);
      h16w[hbase]     = (__bf16)hn2[0];
      h16w[hbase + 1] = (__bf16)hn2[1];
    }
    __syncthreads();                          // all stores acked (vmcnt 0) before release
    if (tid == 0) {
      __threadfence();                        // release: write back L2
      __hip_atomic_fetch_add(cnt, 1u, __ATOMIC_RELAXED, __HIP_MEMORY_SCOPE_AGENT);
    }
  }
}

// ---------------- phase: AR filter over enc (in place, bf16, fp32 math) ------
DEVFN void phase_ar(const Params& P) {
  int gid = blockIdx.x * blockDim.x + threadIdx.x;
  int b = gid >> 9, hi = gid & 511;
  float prev = (float)P.enc[((size_t)60 * B + b) * H + hi];
#pragma unroll
  for (int a = 0; a < 16; ++a) {
    size_t idx = ((size_t)(4 * a) * B + b) * H + hi;
    float cur = (float)P.enc[idx];
    float nv = 0.5f * (cur + prev);
    P.enc[idx] = (__bf16)nv;
    prev = nv;
  }
}

// ---------------- decoder gates -> hd; FAST uses packed bf16 weights ---------
template <bool FAST>
__global__ __launch_bounds__(512) void k_dec_t(Params P) {
  __shared__ float smem[6144];
  const int tid = threadIdx.x;
  const int job = blockIdx.x;
  const int g = job >> 5, bt = (job >> 3) & 3, r = job & 7;
  const int sjt = g * 8 + r;
  const int s = sjt >> 3, jt = sjt & 7;
  const int b0 = bt * 64, j0 = jt * 32;
  const int wave = tid >> 6, lane = tid & 63;
  const int rt = wave >> 1, chalf = wave & 1;
  const int ncol = lane & 15, quad = lane >> 4;
  const int arow = b0 + rt * 16 + ncol;
  const __bf16* aRow = P.enc + ((size_t)(63 - s) * B + arow) * H + quad * 8;

  f32x4 acc[3];
  int gcols[3], pcols[3];
#pragma unroll
  for (int cc = 0; cc < 3; ++cc) {
    const int c = chalf * 3 + cc;
    const int e3 = c >> 1;
    const int gate = (e3 == 0) ? 0 : (e3 + 1);
    const int jw = j0 + (c & 1) * 16 + ncol;
    gcols[cc] = gate * I + jw;
    pcols[cc] = e3 * I + jw;
    float bias = P.bih_dec[s * G4I + gcols[cc]] + P.bhh_dec[s * G4I + gcols[cc]];
    acc[cc] = {bias, bias, bias, bias};
  }
  const float*  bBase = P.Wih_dec + (size_t)s * G4I * H + quad * 8;
  const __bf16* pBase = P.Wdec16  + (size_t)s * G3I * H + quad * 8;
#pragma unroll
  for (int kk = 0; kk < H; kk += 32) {
    bf16x8 af = *(const bf16x8*)(aRow + kk);
#pragma unroll
    for (int cc = 0; cc < 3; ++cc) {
      bf16x8 bf;
      if constexpr (FAST) bf = *(const bf16x8*)(pBase + (size_t)pcols[cc] * H + kk);
      else                bf = loadw8(bBase + (size_t)gcols[cc] * H + kk);
      acc[cc] = __builtin_amdgcn_mfma_f32_16x16x32_bf16(af, bf, acc[cc], 0, 0, 0);
    }
  }
#pragma unroll
  for (int cc = 0; cc < 3; ++cc) {
    const int c = chalf * 3 + cc;
    const int e3 = c >> 1;
    const int jw = (c & 1) * 16 + ncol;
    float* smv = smem + e3 * 2048 + (rt * 16) * 32 + jw;
#pragma unroll
    for (int rr = 0; rr < 4; ++rr) smv[(quad * 4 + rr) * 32] = acc[cc][rr];
  }
  __syncthreads();
  {
    const int row = tid >> 3, jb = (tid & 7) * 4;
    float tmp[4];
#pragma unroll
    for (int u = 0; u < 4; ++u) {
      int j = jb + u;
      float gi = smem[row * 32 + j];
      float gg = smem[2048 + row * 32 + j];
      float go = smem[4096 + row * 32 + j];
      float cv = sigmoidf_(gi) * tanhf_(gg);
      tmp[u] = sigmoidf_(go) * tanhf_(cv);
    }
    float* hout = &P.hd[((size_t)s * B + b0 + row) * I + j0 + jb];
    *(float4*)hout = make_float4(tmp[0], tmp[1], tmp[2], tmp[3]);
  }
}

// ---------------- phase: blockwise cumsum + tanh + transpose out (fp32) ------
DEVFN void phase_out(const Params& P, int job, float* smem) {
  const int tid = threadIdx.x;
  const int b = job >> 2, i0 = (job & 3) * 64;
#pragma unroll
  for (int rep = 0; rep < 8; ++rep) {
    int idx = tid + rep * 512;
    int tt = idx >> 6, ii = idx & 63;
    smem[tt * 66 + ii] = P.hd[((size_t)tt * B + b) * I + i0 + ii];
  }
  __syncthreads();
#pragma unroll
  for (int rep = 0; rep < 2; ++rep) {
    int a = tid & 15;
    int ii = (tid >> 4) + rep * 32;
    float r0 = smem[(4 * a + 0) * 66 + ii];
    float r1 = r0 + smem[(4 * a + 1) * 66 + ii];
    float r2 = r1 + smem[(4 * a + 2) * 66 + ii];
    float r3 = r2 + smem[(4 * a + 3) * 66 + ii];
    float4 v = make_float4(tanhf_(r3), tanhf_(r2), tanhf_(r1), tanhf_(r0));
    *(float4*)&P.out[((size_t)(b * I + i0 + ii)) * S + (60 - 4 * a)] = v;
  }
}

// ---------------- kernels ----------------
__global__ __launch_bounds__(512) void k_transpose(Params P) {
  __shared__ float sm[2112];
  phase_transpose(P, blockIdx.x, sm);
}
__global__ __launch_bounds__(512) void k_step_legacy(Params P, int t) {
  __shared__ float sm[2048];
  phase_step(P, t, blockIdx.x, sm);
}
__global__ __launch_bounds__(512) void k_ar(Params P) { phase_ar(P); }
__global__ __launch_bounds__(512) void k_out(Params P) {
  __shared__ float sm[4224];
  phase_out(P, blockIdx.x, sm);
}

extern "C" void kernel_launch(void* const* d_in, const int* in_sizes, int n_in,
                              void* d_out, int out_size, void* d_ws, size_t ws_size,
                              hipStream_t stream) {
  (void)in_sizes; (void)n_in; (void)out_size;
  char* ws = (char*)d_ws;
  Params P;
  P.x       = (const float*)d_in[0];
  P.Wih_enc = (const float*)d_in[1];
  P.Whh_enc = (const float*)d_in[2];
  P.bih_enc = (const float*)d_in[3];
  P.bhh_enc = (const float*)d_in[4];
  P.Wih_dec = (const float*)d_in[5];
  // d_in[6] = Whh_dec: unused by the reference
  P.bih_dec = (const float*)d_in[7];
  P.bhh_dec = (const float*)d_in[8];

  size_t off = 0;
  P.xT     = (__bf16*)(ws + off); off += (size_t)S * B * I * 2;      //  8,388,608
  P.h32a   = (float*) (ws + off); off += (size_t)B * H * 4;          //    524,288
  P.h16a   = (__bf16*)(ws + off); off += (size_t)B * H * 2;          //    262,144
  P.h32b   = (float*) (ws + off); off += (size_t)B * H * 4;
  P.h16b   = (__bf16*)(ws + off); off += (size_t)B * H * 2;
  P.enc    = (__bf16*)(ws + off); off += (size_t)S * B * H * 2;      // 16,777,216
  P.hd     = (float*) (ws + off); off += (size_t)S * B * I * 4;      // 16,777,216
  P.Whh16  = (__bf16*)(ws + off); off += (size_t)S * G4H * H * 2;    // 134,217,728
  P.Wdec16 = (__bf16*)(ws + off); off += (size_t)S * G3I * H * 2;    //  50,331,648
  P.xg     = (float*) (ws + off); off += (size_t)S * B * G4H * 4;    // 134,217,728
  P.sync   = (unsigned*)(ws + off); off += 256;
  P.out    = (float*)d_out;
  const size_t NEED_FAST = off;   // ~496 MB

  bool fast = ws_size >= NEED_FAST;
  if (fast &&
      hipFuncSetAttribute(reinterpret_cast<const void*>(&k_enc),
                          hipFuncAttributeMaxDynamicSharedMemorySize,
                          (int)LDS_ENC) != hipSuccess) {
    fast = false;
  }

  // zero h slot 0 (h32a + h16a contiguous) and the sync counters
  hipMemsetAsync((char*)P.h32a, 0, (size_t)B * H * 4 + (size_t)B * H * 2, stream);

  if (fast) {
    hipMemsetAsync((char*)P.sync, 0, 256, stream);
    k_transpose<<<1024, 512, 0, stream>>>(P);
    k_xg<<<4096, 512, 0, stream>>>(P);                               // x-part gates
    k_cvt<<<16384, 512, 0, stream>>>(P.Whh_enc, P.Whh16);            // 67.1M elems
    k_enc<<<128, 512, LDS_ENC, stream>>>(P);                         // all 64 steps
    k_ar<<<256, 512, 0, stream>>>(P);
    k_cvt_dec<<<6144, 512, 0, stream>>>(P.Wih_dec, P.Wdec16);
    k_dec_t<true><<<2048, 512, 0, stream>>>(P);
    k_out<<<1024, 512, 0, stream>>>(P);
  } else {
    k_transpose<<<1024, 512, 0, stream>>>(P);
    for (int t = 0; t < S; ++t) k_step_legacy<<<256, 512, 0, stream>>>(P, t);
    k_ar<<<256, 512, 0, stream>>>(P);
    k_dec_t<false><<<2048, 512, 0, stream>>>(P);
    k_out<<<1024, 512, 0, stream>>>(P);
  }
}